// Round 2
// baseline (1251.440 us; speedup 1.0000x reference)
//
#include <hip/hip_runtime.h>

#define N_NODES 50000
#define N_REL 16
#define N_BASIS 8
#define D_IN 64
#define D_HID 64
#define N_CLASS 16
#define N_EDGES 800000

// ---------------- counts[r,n] histogram ----------------
__global__ __launch_bounds__(256) void k_counts(const int* __restrict__ et,
                                                const int* __restrict__ ei,
                                                int* __restrict__ counts) {
    int e = blockIdx.x * 256 + threadIdx.x;
    if (e < N_EDGES) {
        int dst = ei[N_EDGES + e];
        int t = et[e];
        atomicAdd(&counts[t * N_NODES + dst], 1);
    }
}

// ---------------- W_r = sum_b coeffs[r,b] * bases[b] ----------------
__global__ __launch_bounds__(256) void k_wrel(const float* __restrict__ b1, const float* __restrict__ c1,
                                              const float* __restrict__ b2, const float* __restrict__ c2,
                                              float* __restrict__ w1, float* __restrict__ w2) {
    int idx = blockIdx.x * 256 + threadIdx.x;
    if (idx < N_REL * D_IN * D_HID) {
        int r = idx >> 12;            // /4096
        int io = idx & 4095;
        float acc = 0.f;
        #pragma unroll
        for (int b = 0; b < N_BASIS; b++) acc += c1[r * N_BASIS + b] * b1[b * 4096 + io];
        w1[idx] = acc;
    }
    int idx2 = idx - N_REL * D_IN * D_HID;
    if (idx2 >= 0 && idx2 < N_REL * D_HID * N_CLASS) {
        int r = idx2 >> 10;           // /1024
        int io = idx2 & 1023;
        float acc = 0.f;
        #pragma unroll
        for (int b = 0; b < N_BASIS; b++) acc += c2[r * N_BASIS + b] * b2[b * 1024 + io];
        w2[idx2] = acc;
    }
}

// ---------------- layer-1 transform: t1[r,n,:] = x[n,:] @ W_r ; h = x @ self1 ----------------
__global__ __launch_bounds__(256) void k_gemm1(const float* __restrict__ x, const float* __restrict__ w1,
                                               const float* __restrict__ self1,
                                               float* __restrict__ t1, float* __restrict__ h) {
    __shared__ float xs[64][65];      // padded: stride 65 -> 2-way bank alias (free)
    __shared__ float ws[64 * 64];     // unpadded: float4-aligned broadcast reads
    int n0 = blockIdx.x * 64;
    int tid = threadIdx.x;
    int row = tid & 63;               // wave-uniform cg per wave
    int cg  = tid >> 6;               // 0..3 -> 16 cols each

    #pragma unroll
    for (int i = 0; i < 16; i++) {
        int idx = tid + i * 256;
        int r = idx >> 6, c = idx & 63;
        int n = n0 + r;
        xs[r][c] = (n < N_NODES) ? x[(size_t)n * 64 + c] : 0.f;
    }
    __syncthreads();

    for (int w = 0; w < 17; w++) {
        const float* W = (w < 16) ? (w1 + w * 4096) : self1;
        #pragma unroll
        for (int i = 0; i < 16; i++) {
            int idx = tid + i * 256;
            ws[idx] = W[idx];
        }
        __syncthreads();

        float acc[16];
        #pragma unroll
        for (int j = 0; j < 16; j++) acc[j] = 0.f;

        for (int k = 0; k < 64; k++) {
            float a = xs[row][k];
            const float4* wr = (const float4*)(ws + k * 64 + cg * 16);
            float4 b0 = wr[0], b1 = wr[1], b2 = wr[2], b3 = wr[3];
            acc[0]  += a * b0.x; acc[1]  += a * b0.y; acc[2]  += a * b0.z; acc[3]  += a * b0.w;
            acc[4]  += a * b1.x; acc[5]  += a * b1.y; acc[6]  += a * b1.z; acc[7]  += a * b1.w;
            acc[8]  += a * b2.x; acc[9]  += a * b2.y; acc[10] += a * b2.z; acc[11] += a * b2.w;
            acc[12] += a * b3.x; acc[13] += a * b3.y; acc[14] += a * b3.z; acc[15] += a * b3.w;
        }

        int n = n0 + row;
        if (n < N_NODES) {
            float* dst = (w < 16) ? (t1 + ((size_t)w * N_NODES + n) * 64 + cg * 16)
                                  : (h + (size_t)n * 64 + cg * 16);
            #pragma unroll
            for (int j4 = 0; j4 < 4; j4++) {
                *(float4*)(dst + j4 * 4) =
                    make_float4(acc[j4 * 4], acc[j4 * 4 + 1], acc[j4 * 4 + 2], acc[j4 * 4 + 3]);
            }
        }
        __syncthreads();
    }
}

// ---------------- layer-1 edge scatter: h[dst] += inv_c * t1[type, src] ----------------
__global__ __launch_bounds__(256) void k_edge1(const int* __restrict__ ei, const int* __restrict__ et,
                                               const int* __restrict__ counts,
                                               const float* __restrict__ t1, float* __restrict__ h) {
    int tid = threadIdx.x;
    int e = blockIdx.x * 16 + (tid >> 4);
    int l = tid & 15;
    if (e >= N_EDGES) return;
    int src = ei[e];
    int dst = ei[N_EDGES + e];
    int t = et[e];
    float inv = 1.0f / (float)counts[t * N_NODES + dst];
    float4 v = *(const float4*)(t1 + ((size_t)t * N_NODES + src) * 64 + l * 4);
    float* dp = h + (size_t)dst * 64 + l * 4;
    atomicAdd(dp + 0, inv * v.x);
    atomicAdd(dp + 1, inv * v.y);
    atomicAdd(dp + 2, inv * v.z);
    atomicAdd(dp + 3, inv * v.w);
}

// ---------------- layer-2 transform: t2[r,n,:] = relu(h)[n,:] @ W2_r ; out = relu(h) @ self2 ----------------
__global__ __launch_bounds__(256) void k_gemm2(const float* __restrict__ h, const float* __restrict__ w2,
                                               const float* __restrict__ self2,
                                               float* __restrict__ t2, float* __restrict__ out) {
    __shared__ float hs[64][65];
    __shared__ float ws[64 * 16];
    int n0 = blockIdx.x * 64;
    int tid = threadIdx.x;
    int row = tid & 63;
    int cg  = tid >> 6;               // 0..3 -> 4 cols each

    #pragma unroll
    for (int i = 0; i < 16; i++) {
        int idx = tid + i * 256;
        int r = idx >> 6, c = idx & 63;
        int n = n0 + r;
        float v = (n < N_NODES) ? h[(size_t)n * 64 + c] : 0.f;
        hs[r][c] = v > 0.f ? v : 0.f;   // fused relu
    }
    __syncthreads();

    for (int w = 0; w < 17; w++) {
        const float* W = (w < 16) ? (w2 + w * 1024) : self2;
        {
            int idx = tid * 4;          // 256*4 = 1024 floats
            *(float4*)(ws + idx) = *(const float4*)(W + idx);
        }
        __syncthreads();

        float4 acc = make_float4(0.f, 0.f, 0.f, 0.f);
        for (int k = 0; k < 64; k++) {
            float a = hs[row][k];
            float4 b = *(const float4*)(ws + k * 16 + cg * 4);
            acc.x += a * b.x; acc.y += a * b.y; acc.z += a * b.z; acc.w += a * b.w;
        }

        int n = n0 + row;
        if (n < N_NODES) {
            float* dst = (w < 16) ? (t2 + ((size_t)w * N_NODES + n) * 16 + cg * 4)
                                  : (out + (size_t)n * 16 + cg * 4);
            *(float4*)dst = acc;
        }
        __syncthreads();
    }
}

// ---------------- layer-2 edge scatter: out[dst] += inv_c * t2[type, src] ----------------
__global__ __launch_bounds__(256) void k_edge2(const int* __restrict__ ei, const int* __restrict__ et,
                                               const int* __restrict__ counts,
                                               const float* __restrict__ t2, float* __restrict__ out) {
    int tid = threadIdx.x;
    int e = blockIdx.x * 64 + (tid >> 2);
    int l = tid & 3;
    if (e >= N_EDGES) return;
    int src = ei[e];
    int dst = ei[N_EDGES + e];
    int t = et[e];
    float inv = 1.0f / (float)counts[t * N_NODES + dst];
    float4 v = *(const float4*)(t2 + ((size_t)t * N_NODES + src) * 16 + l * 4);
    float* dp = out + (size_t)dst * 16 + l * 4;
    atomicAdd(dp + 0, inv * v.x);
    atomicAdd(dp + 1, inv * v.y);
    atomicAdd(dp + 2, inv * v.z);
    atomicAdd(dp + 3, inv * v.w);
}

extern "C" void kernel_launch(void* const* d_in, const int* in_sizes, int n_in,
                              void* d_out, int out_size, void* d_ws, size_t ws_size,
                              hipStream_t stream) {
    const float* x      = (const float*)d_in[0];
    const float* bases1 = (const float*)d_in[1];
    const float* coeffs1= (const float*)d_in[2];
    const float* self1  = (const float*)d_in[3];
    const float* bases2 = (const float*)d_in[4];
    const float* coeffs2= (const float*)d_in[5];
    const float* self2  = (const float*)d_in[6];
    const int*   ei     = (const int*)d_in[7];   // [2, E]
    const int*   et     = (const int*)d_in[8];   // [E]
    float* out = (float*)d_out;

    char* ws = (char*)d_ws;
    // workspace layout — total 221,127,680 B (~211 MiB), fits a 256 MiB ws.
    // t2 ALIASES t1's region: t1 is dead after k_edge1, t2 written after (stream order).
    int*   counts = (int*)(ws + 0);                 //  3,200,000 B
    float* w1     = (float*)(ws + 3200000);         //    262,144 B
    float* w2     = (float*)(ws + 3462144);         //     65,536 B
    float* h      = (float*)(ws + 3527680);         // 12,800,000 B
    float* t1     = (float*)(ws + 16327680);        // 204,800,000 B -> end 221,127,680
    float* t2     = t1;                             // 51,200,000 B alias (safe: sequential lifetimes)

    hipMemsetAsync(counts, 0, (size_t)N_REL * N_NODES * sizeof(int), stream);
    k_counts<<<(N_EDGES + 255) / 256, 256, 0, stream>>>(et, ei, counts);
    k_wrel<<<(N_REL * D_IN * D_HID + N_REL * D_HID * N_CLASS + 255) / 256, 256, 0, stream>>>(
        bases1, coeffs1, bases2, coeffs2, w1, w2);
    k_gemm1<<<(N_NODES + 63) / 64, 256, 0, stream>>>(x, w1, self1, t1, h);
    k_edge1<<<(N_EDGES + 15) / 16, 256, 0, stream>>>(ei, et, counts, t1, h);
    k_gemm2<<<(N_NODES + 63) / 64, 256, 0, stream>>>(h, w2, self2, t2, out);
    k_edge2<<<(N_EDGES + 63) / 64, 256, 0, stream>>>(ei, et, counts, t2, out);
}

// Round 3
// 604.313 us; speedup vs baseline: 2.0708x; 2.0708x over previous
//
#include <hip/hip_runtime.h>

#define N_NODES 50000
#define N_REL 16
#define N_BASIS 8
#define D_IN 64
#define D_HID 64
#define N_CLASS 16
#define N_EDGES 800000
#define N_SBLK 196   // ceil(50000/256)

// ---------------- histogram: counts[r,n] and deg[n] ----------------
__global__ __launch_bounds__(256) void k_counts(const int* __restrict__ et,
                                                const int* __restrict__ ei,
                                                int* __restrict__ counts,
                                                int* __restrict__ deg) {
    int e = blockIdx.x * 256 + threadIdx.x;
    if (e < N_EDGES) {
        int dst = ei[N_EDGES + e];
        int t = et[e];
        atomicAdd(&counts[t * N_NODES + dst], 1);
        atomicAdd(&deg[dst], 1);
    }
}

// ---------------- W_r = sum_b coeffs[r,b] * bases[b] ----------------
__global__ __launch_bounds__(256) void k_wrel(const float* __restrict__ b1, const float* __restrict__ c1,
                                              const float* __restrict__ b2, const float* __restrict__ c2,
                                              float* __restrict__ w1, float* __restrict__ w2) {
    int idx = blockIdx.x * 256 + threadIdx.x;
    if (idx < N_REL * D_IN * D_HID) {
        int r = idx >> 12;
        int io = idx & 4095;
        float acc = 0.f;
        #pragma unroll
        for (int b = 0; b < N_BASIS; b++) acc += c1[r * N_BASIS + b] * b1[b * 4096 + io];
        w1[idx] = acc;
    }
    int idx2 = idx - N_REL * D_IN * D_HID;
    if (idx2 >= 0 && idx2 < N_REL * D_HID * N_CLASS) {
        int r = idx2 >> 10;
        int io = idx2 & 1023;
        float acc = 0.f;
        #pragma unroll
        for (int b = 0; b < N_BASIS; b++) acc += c2[r * N_BASIS + b] * b2[b * 1024 + io];
        w2[idx2] = acc;
    }
}

// ---------------- scan stage 1: per-block exclusive scan of deg -> offsets, block total -> bsum ----------------
__global__ __launch_bounds__(256) void k_scan_local(const int* __restrict__ deg,
                                                    int* __restrict__ offsets,
                                                    int* __restrict__ bsum) {
    __shared__ int s[256];
    int t = threadIdx.x;
    int i = blockIdx.x * 256 + t;
    int v = (i < N_NODES) ? deg[i] : 0;
    s[t] = v;
    __syncthreads();
    #pragma unroll
    for (int off = 1; off < 256; off <<= 1) {
        int x = (t >= off) ? s[t - off] : 0;
        __syncthreads();
        s[t] += x;
        __syncthreads();
    }
    if (i < N_NODES) offsets[i] = s[t] - v;      // exclusive within block
    if (t == 255) bsum[blockIdx.x] = s[255];     // block total
}

// ---------------- scan stage 2: exclusive scan of bsum (single block) ----------------
__global__ __launch_bounds__(256) void k_scan_bsum(int* __restrict__ bsum) {
    __shared__ int s[256];
    int t = threadIdx.x;
    int v = (t < N_SBLK) ? bsum[t] : 0;
    s[t] = v;
    __syncthreads();
    #pragma unroll
    for (int off = 1; off < 256; off <<= 1) {
        int x = (t >= off) ? s[t - off] : 0;
        __syncthreads();
        s[t] += x;
        __syncthreads();
    }
    if (t < N_SBLK) bsum[t] = s[t] - v;          // exclusive
}

// ---------------- scan stage 3: add block base; init cursor; seal offsets[N] ----------------
__global__ __launch_bounds__(256) void k_scan_final(int* __restrict__ offsets,
                                                    const int* __restrict__ bsum,
                                                    int* __restrict__ cursor) {
    int i = blockIdx.x * 256 + threadIdx.x;
    if (i < N_NODES) {
        int o = offsets[i] + bsum[blockIdx.x];
        offsets[i] = o;
        cursor[i] = o;
    }
    if (i == 0) offsets[N_NODES] = N_EDGES;
}

// ---------------- scatter edges into dst-sorted order ----------------
__global__ __launch_bounds__(256) void k_scatter(const int* __restrict__ ei, const int* __restrict__ et,
                                                 const int* __restrict__ counts,
                                                 int* __restrict__ cursor,
                                                 int* __restrict__ srow, float* __restrict__ sinv) {
    int e = blockIdx.x * 256 + threadIdx.x;
    if (e >= N_EDGES) return;
    int src = ei[e];
    int dst = ei[N_EDGES + e];
    int t = et[e];
    int pos = atomicAdd(&cursor[dst], 1);
    srow[pos] = t * N_NODES + src;
    sinv[pos] = 1.0f / (float)counts[t * N_NODES + dst];
}

// ---------------- layer-1 transform: t1[r,n,:] = x[n,:] @ W_r ; h = x @ self1 ----------------
__global__ __launch_bounds__(256) void k_gemm1(const float* __restrict__ x, const float* __restrict__ w1,
                                               const float* __restrict__ self1,
                                               float* __restrict__ t1, float* __restrict__ h) {
    __shared__ float xs[64][65];
    __shared__ float ws[64 * 64];
    int n0 = blockIdx.x * 64;
    int tid = threadIdx.x;
    int row = tid & 63;
    int cg  = tid >> 6;

    #pragma unroll
    for (int i = 0; i < 16; i++) {
        int idx = tid + i * 256;
        int r = idx >> 6, c = idx & 63;
        int n = n0 + r;
        xs[r][c] = (n < N_NODES) ? x[(size_t)n * 64 + c] : 0.f;
    }
    __syncthreads();

    for (int w = 0; w < 17; w++) {
        const float* W = (w < 16) ? (w1 + w * 4096) : self1;
        #pragma unroll
        for (int i = 0; i < 16; i++) {
            int idx = tid + i * 256;
            ws[idx] = W[idx];
        }
        __syncthreads();

        float acc[16];
        #pragma unroll
        for (int j = 0; j < 16; j++) acc[j] = 0.f;

        for (int k = 0; k < 64; k++) {
            float a = xs[row][k];
            const float4* wr = (const float4*)(ws + k * 64 + cg * 16);
            float4 b0 = wr[0], b1 = wr[1], b2 = wr[2], b3 = wr[3];
            acc[0]  += a * b0.x; acc[1]  += a * b0.y; acc[2]  += a * b0.z; acc[3]  += a * b0.w;
            acc[4]  += a * b1.x; acc[5]  += a * b1.y; acc[6]  += a * b1.z; acc[7]  += a * b1.w;
            acc[8]  += a * b2.x; acc[9]  += a * b2.y; acc[10] += a * b2.z; acc[11] += a * b2.w;
            acc[12] += a * b3.x; acc[13] += a * b3.y; acc[14] += a * b3.z; acc[15] += a * b3.w;
        }

        int n = n0 + row;
        if (n < N_NODES) {
            float* dst = (w < 16) ? (t1 + ((size_t)w * N_NODES + n) * 64 + cg * 16)
                                  : (h + (size_t)n * 64 + cg * 16);
            #pragma unroll
            for (int j4 = 0; j4 < 4; j4++) {
                *(float4*)(dst + j4 * 4) =
                    make_float4(acc[j4 * 4], acc[j4 * 4 + 1], acc[j4 * 4 + 2], acc[j4 * 4 + 3]);
            }
        }
        __syncthreads();
    }
}

// ---------------- layer-1 aggregation: one wave per dst node, no atomics ----------------
__global__ __launch_bounds__(256) void k_agg1(const int* __restrict__ offsets,
                                              const int* __restrict__ srow, const float* __restrict__ sinv,
                                              const float* __restrict__ t1, float* __restrict__ h) {
    int tid = threadIdx.x;
    int n = blockIdx.x * 4 + (tid >> 6);   // 12500*4 = 50000 exact
    int lane = tid & 63;
    int start = offsets[n];
    int end = offsets[n + 1];
    float acc = 0.f;
    for (int i = start; i < end; i++) {
        int row = srow[i];                  // wave-uniform broadcast load
        float inv = sinv[i];
        acc += inv * t1[(size_t)row * 64 + lane];
    }
    h[(size_t)n * 64 + lane] += acc;        // on top of self term; unique owner
}

// ---------------- layer-2 transform: t2[r,n,:] = relu(h) @ W2_r ; out = relu(h) @ self2 ----------------
__global__ __launch_bounds__(256) void k_gemm2(const float* __restrict__ h, const float* __restrict__ w2,
                                               const float* __restrict__ self2,
                                               float* __restrict__ t2, float* __restrict__ out) {
    __shared__ float hs[64][65];
    __shared__ float ws[64 * 16];
    int n0 = blockIdx.x * 64;
    int tid = threadIdx.x;
    int row = tid & 63;
    int cg  = tid >> 6;

    #pragma unroll
    for (int i = 0; i < 16; i++) {
        int idx = tid + i * 256;
        int r = idx >> 6, c = idx & 63;
        int n = n0 + r;
        float v = (n < N_NODES) ? h[(size_t)n * 64 + c] : 0.f;
        hs[r][c] = v > 0.f ? v : 0.f;
    }
    __syncthreads();

    for (int w = 0; w < 17; w++) {
        const float* W = (w < 16) ? (w2 + w * 1024) : self2;
        {
            int idx = tid * 4;
            *(float4*)(ws + idx) = *(const float4*)(W + idx);
        }
        __syncthreads();

        float4 acc = make_float4(0.f, 0.f, 0.f, 0.f);
        for (int k = 0; k < 64; k++) {
            float a = hs[row][k];
            float4 b = *(const float4*)(ws + k * 16 + cg * 4);
            acc.x += a * b.x; acc.y += a * b.y; acc.z += a * b.z; acc.w += a * b.w;
        }

        int n = n0 + row;
        if (n < N_NODES) {
            float* dst = (w < 16) ? (t2 + ((size_t)w * N_NODES + n) * 16 + cg * 4)
                                  : (out + (size_t)n * 16 + cg * 4);
            *(float4*)dst = acc;
        }
        __syncthreads();
    }
}

// ---------------- layer-2 aggregation: quarter-wave per dst node, no atomics ----------------
__global__ __launch_bounds__(256) void k_agg2(const int* __restrict__ offsets,
                                              const int* __restrict__ srow, const float* __restrict__ sinv,
                                              const float* __restrict__ t2, float* __restrict__ out) {
    int tid = threadIdx.x;
    int n = blockIdx.x * 16 + (tid >> 4);  // 3125*16 = 50000 exact
    int l = tid & 15;
    int start = offsets[n];
    int end = offsets[n + 1];
    float acc = 0.f;
    for (int i = start; i < end; i++) {
        int row = srow[i];
        float inv = sinv[i];
        acc += inv * t2[(size_t)row * 16 + l];
    }
    out[(size_t)n * 16 + l] += acc;         // on top of self term; unique owner
}

extern "C" void kernel_launch(void* const* d_in, const int* in_sizes, int n_in,
                              void* d_out, int out_size, void* d_ws, size_t ws_size,
                              hipStream_t stream) {
    const float* x      = (const float*)d_in[0];
    const float* bases1 = (const float*)d_in[1];
    const float* coeffs1= (const float*)d_in[2];
    const float* self1  = (const float*)d_in[3];
    const float* bases2 = (const float*)d_in[4];
    const float* coeffs2= (const float*)d_in[5];
    const float* self2  = (const float*)d_in[6];
    const int*   ei     = (const int*)d_in[7];   // [2, E]
    const int*   et     = (const int*)d_in[8];   // [E]
    float* out = (float*)d_out;

    char* ws = (char*)d_ws;
    // workspace layout (~217.6 MB total, < 256 MiB)
    int*   counts  = (int*)(ws + 0);              //  3,200,000
    int*   deg     = (int*)(ws + 3200000);        //    200,000  (memset with counts)
    int*   offsets = (int*)(ws + 3400064);        //    200,004
    int*   cursor  = (int*)(ws + 3600128);        //    200,000
    float* w1      = (float*)(ws + 3800192);      //    262,144
    float* w2      = (float*)(ws + 4062336);      //     65,536
    int*   bsum    = (int*)(ws + 4127872);        //      1,024
    int*   srow    = (int*)(ws + 4128896);        //  3,200,000
    float* sinv    = (float*)(ws + 7328896);      //  3,200,000
    float* h       = (float*)(ws + 10528960);     // 12,800,000
    float* t1      = (float*)(ws + 23329024);     // 204,800,000 -> end 228,129,024
    float* t2      = t1;                          // alias: t1 dead after k_agg1

    hipMemsetAsync(counts, 0, 3400000, stream);   // counts + deg
    k_counts<<<(N_EDGES + 255) / 256, 256, 0, stream>>>(et, ei, counts, deg);
    k_wrel<<<(N_REL * D_IN * D_HID + N_REL * D_HID * N_CLASS + 255) / 256, 256, 0, stream>>>(
        bases1, coeffs1, bases2, coeffs2, w1, w2);
    k_scan_local<<<N_SBLK, 256, 0, stream>>>(deg, offsets, bsum);
    k_scan_bsum<<<1, 256, 0, stream>>>(bsum);
    k_scan_final<<<N_SBLK, 256, 0, stream>>>(offsets, bsum, cursor);
    k_scatter<<<(N_EDGES + 255) / 256, 256, 0, stream>>>(ei, et, counts, cursor, srow, sinv);
    k_gemm1<<<(N_NODES + 63) / 64, 256, 0, stream>>>(x, w1, self1, t1, h);
    k_agg1<<<12500, 256, 0, stream>>>(offsets, srow, sinv, t1, h);
    k_gemm2<<<(N_NODES + 63) / 64, 256, 0, stream>>>(h, w2, self2, t2, out);
    k_agg2<<<3125, 256, 0, stream>>>(offsets, srow, sinv, t2, out);
}

// Round 4
// 326.250 us; speedup vs baseline: 3.8358x; 1.8523x over previous
//
#include <hip/hip_runtime.h>

#define N_NODES 50000
#define N_REL 16
#define N_BASIS 8
#define D_IN 64
#define D_HID 64
#define N_CLASS 16
#define N_EDGES 800000
#define N_SBLK 196   // ceil(50000/256)

typedef short s8v __attribute__((ext_vector_type(8)));    // 8 bf16 (4 VGPRs) MFMA A/B frag
typedef float f4v __attribute__((ext_vector_type(4)));    // 4 fp32 MFMA C/D frag

__device__ inline unsigned short f2bf(float f) {
    union { float f; unsigned u; } v; v.f = f;
    unsigned r = (v.u + 0x7FFFu + ((v.u >> 16) & 1u)) >> 16;   // RNE
    return (unsigned short)r;
}
__device__ inline float bf2f(unsigned short b) {
    union { unsigned u; float f; } v; v.u = ((unsigned)b) << 16;
    return v.f;
}

// ---------------- histogram: counts[r,n] ----------------
__global__ __launch_bounds__(256) void k_counts(const int* __restrict__ et,
                                                const int* __restrict__ ei,
                                                int* __restrict__ counts) {
    int e = blockIdx.x * 256 + threadIdx.x;
    if (e < N_EDGES) {
        int dst = ei[N_EDGES + e];
        int t = et[e];
        atomicAdd(&counts[t * N_NODES + dst], 1);
    }
}

// ---------------- W_r = sum_b coeffs[r,b] * bases[b] ----------------
__global__ __launch_bounds__(256) void k_wrel(const float* __restrict__ b1, const float* __restrict__ c1,
                                              const float* __restrict__ b2, const float* __restrict__ c2,
                                              float* __restrict__ w1, float* __restrict__ w2) {
    int idx = blockIdx.x * 256 + threadIdx.x;
    if (idx < N_REL * D_IN * D_HID) {
        int r = idx >> 12;
        int io = idx & 4095;
        float acc = 0.f;
        #pragma unroll
        for (int b = 0; b < N_BASIS; b++) acc += c1[r * N_BASIS + b] * b1[b * 4096 + io];
        w1[idx] = acc;
    }
    int idx2 = idx - N_REL * D_IN * D_HID;
    if (idx2 >= 0 && idx2 < N_REL * D_HID * N_CLASS) {
        int r = idx2 >> 10;
        int io = idx2 & 1023;
        float acc = 0.f;
        #pragma unroll
        for (int b = 0; b < N_BASIS; b++) acc += c2[r * N_BASIS + b] * b2[b * 1024 + io];
        w2[idx2] = acc;
    }
}

// ---------------- scan stage 1: deg[n] = sum_r counts[r,n]; block-local exclusive scan ----------------
__global__ __launch_bounds__(256) void k_scan_local(const int* __restrict__ counts,
                                                    int* __restrict__ offsets,
                                                    int* __restrict__ bsum) {
    __shared__ int s[256];
    int t = threadIdx.x;
    int i = blockIdx.x * 256 + t;
    int v = 0;
    if (i < N_NODES) {
        #pragma unroll
        for (int r = 0; r < N_REL; r++) v += counts[r * N_NODES + i];
    }
    s[t] = v;
    __syncthreads();
    #pragma unroll
    for (int off = 1; off < 256; off <<= 1) {
        int x = (t >= off) ? s[t - off] : 0;
        __syncthreads();
        s[t] += x;
        __syncthreads();
    }
    if (i < N_NODES) offsets[i] = s[t] - v;
    if (t == 255) bsum[blockIdx.x] = s[255];
}

// ---------------- scan stage 2 ----------------
__global__ __launch_bounds__(256) void k_scan_bsum(int* __restrict__ bsum) {
    __shared__ int s[256];
    int t = threadIdx.x;
    int v = (t < N_SBLK) ? bsum[t] : 0;
    s[t] = v;
    __syncthreads();
    #pragma unroll
    for (int off = 1; off < 256; off <<= 1) {
        int x = (t >= off) ? s[t - off] : 0;
        __syncthreads();
        s[t] += x;
        __syncthreads();
    }
    if (t < N_SBLK) bsum[t] = s[t] - v;
}

// ---------------- scan stage 3 ----------------
__global__ __launch_bounds__(256) void k_scan_final(int* __restrict__ offsets,
                                                    const int* __restrict__ bsum,
                                                    int* __restrict__ cursor) {
    int i = blockIdx.x * 256 + threadIdx.x;
    if (i < N_NODES) {
        int o = offsets[i] + bsum[blockIdx.x];
        offsets[i] = o;
        cursor[i] = o;
    }
    if (i == 0) offsets[N_NODES] = N_EDGES;
}

// ---------------- scatter edges into dst-sorted order (packed int2) ----------------
__global__ __launch_bounds__(256) void k_scatter(const int* __restrict__ ei, const int* __restrict__ et,
                                                 const int* __restrict__ counts,
                                                 int* __restrict__ cursor,
                                                 int2* __restrict__ sedge) {
    int e = blockIdx.x * 256 + threadIdx.x;
    if (e >= N_EDGES) return;
    int src = ei[e];
    int dst = ei[N_EDGES + e];
    int t = et[e];
    int pos = atomicAdd(&cursor[dst], 1);
    float inv = 1.0f / (float)counts[t * N_NODES + dst];
    sedge[pos] = make_int2(t * N_NODES + src, __float_as_int(inv));
}

// ---------------- layer-1 MFMA transform: t1[r,n,:]=x@W_r (bf16), h=x@self1 (bf16) ----------------
__global__ __launch_bounds__(256) void k_gemm1(const float* __restrict__ x, const float* __restrict__ w1,
                                               const float* __restrict__ self1,
                                               unsigned short* __restrict__ t1, unsigned short* __restrict__ h) {
    __shared__ __align__(16) unsigned short xs[64][72];
    __shared__ __align__(16) unsigned short wsT[64][72];   // transposed: wsT[col][k]
    __shared__ __align__(16) unsigned short outs[64][72];
    int tid = threadIdx.x;
    int n0 = blockIdx.x * 64;
    int wv = tid >> 6, lane = tid & 63;
    int m = lane & 15, q = lane >> 4;

    // stage x tile fp32 -> bf16
    #pragma unroll
    for (int i = 0; i < 16; i++) {
        int idx = tid + i * 256;
        int r = idx >> 6, c = idx & 63;
        int n = n0 + r;
        float v = (n < N_NODES) ? x[(size_t)n * 64 + c] : 0.f;
        xs[r][c] = f2bf(v);
    }
    __syncthreads();

    // A fragments held in registers across all 17 weights
    s8v a0 = *(const s8v*)&xs[wv * 16 + m][q * 8];
    s8v a1 = *(const s8v*)&xs[wv * 16 + m][32 + q * 8];

    int sc = tid & 63;        // staging col
    int skg = tid >> 6;       // staging k-group

    for (int w = 0; w < 17; w++) {
        const float* W = (w < 16) ? (w1 + w * 4096) : self1;
        // stage W transposed -> wsT[col][k], packed uint writes
        #pragma unroll
        for (int jp = 0; jp < 8; jp++) {
            int k = skg * 16 + jp * 2;
            unsigned pk = (unsigned)f2bf(W[k * 64 + sc]) | ((unsigned)f2bf(W[(k + 1) * 64 + sc]) << 16);
            *(unsigned*)&wsT[sc][k] = pk;
        }
        __syncthreads();

        f4v acc[4];
        #pragma unroll
        for (int ct = 0; ct < 4; ct++) {
            acc[ct] = (f4v){0.f, 0.f, 0.f, 0.f};
            s8v b0 = *(const s8v*)&wsT[ct * 16 + m][q * 8];
            s8v b1 = *(const s8v*)&wsT[ct * 16 + m][32 + q * 8];
            acc[ct] = __builtin_amdgcn_mfma_f32_16x16x32_bf16(a0, b0, acc[ct], 0, 0, 0);
            acc[ct] = __builtin_amdgcn_mfma_f32_16x16x32_bf16(a1, b1, acc[ct], 0, 0, 0);
        }
        // epilogue: accs -> LDS (bf16)
        #pragma unroll
        for (int ct = 0; ct < 4; ct++) {
            #pragma unroll
            for (int r = 0; r < 4; r++) {
                outs[wv * 16 + q * 4 + r][ct * 16 + m] = f2bf(acc[ct][r]);
            }
        }
        __syncthreads();

        // coalesced store: 64 rows x 128 B contiguous
        int row = tid >> 2, cq = tid & 3;
        int n = n0 + row;
        if (n < N_NODES) {
            int4 d0 = *(const int4*)&outs[row][cq * 16];
            int4 d1 = *(const int4*)&outs[row][cq * 16 + 8];
            unsigned short* dst = (w < 16) ? (t1 + ((size_t)w * N_NODES + n) * 64 + cq * 16)
                                           : (h + (size_t)n * 64 + cq * 16);
            *(int4*)dst = d0;
            *(int4*)(dst + 8) = d1;
        }
        // next iteration's syncthreads (after wsT staging) protects outs reuse
    }
}

// ---------------- layer-1 aggregation: one wave per dst node ----------------
__global__ __launch_bounds__(256) void k_agg1(const int* __restrict__ offsets,
                                              const int2* __restrict__ sedge,
                                              const unsigned short* __restrict__ t1,
                                              unsigned short* __restrict__ h) {
    int tid = threadIdx.x;
    int n = blockIdx.x * 4 + (tid >> 6);
    int lane = tid & 63;
    int start = offsets[n];
    int end = offsets[n + 1];
    float acc = 0.f;
    for (int i = start; i < end; i++) {
        int2 e = sedge[i];
        float inv = __int_as_float(e.y);
        acc += inv * bf2f(t1[(size_t)e.x * 64 + lane]);
    }
    size_t hi = (size_t)n * 64 + lane;
    h[hi] = f2bf(bf2f(h[hi]) + acc);   // on top of self term; unique owner
}

// ---------------- layer-2 MFMA transform: t2[r,n,:]=relu(h)@W2_r (bf16), out=relu(h)@self2 (fp32) ----------------
__global__ __launch_bounds__(256) void k_gemm2(const unsigned short* __restrict__ h, const float* __restrict__ w2,
                                               const float* __restrict__ self2,
                                               unsigned short* __restrict__ t2, float* __restrict__ out) {
    __shared__ __align__(16) unsigned short xs[64][72];
    __shared__ __align__(16) unsigned short wsT[16][72];
    __shared__ __align__(16) unsigned short outs[64][24];
    int tid = threadIdx.x;
    int n0 = blockIdx.x * 64;
    int wv = tid >> 6, lane = tid & 63;
    int m = lane & 15, q = lane >> 4;

    // stage relu(h) tile (bf16, packed uint)
    const unsigned* hb = (const unsigned*)h;
    #pragma unroll
    for (int i = 0; i < 8; i++) {
        int idx = tid + i * 256;          // 2048 uints
        int r = idx >> 5, c2 = idx & 31;
        int n = n0 + r;
        unsigned v = (n < N_NODES) ? hb[(size_t)n * 32 + c2] : 0u;
        unsigned lo = v & 0xFFFFu, hi = v >> 16;
        if (lo & 0x8000u) lo = 0u;        // relu on bf16 halves
        if (hi & 0x8000u) hi = 0u;
        *(unsigned*)&xs[r][c2 * 2] = lo | (hi << 16);
    }
    __syncthreads();

    s8v a0 = *(const s8v*)&xs[wv * 16 + m][q * 8];
    s8v a1 = *(const s8v*)&xs[wv * 16 + m][32 + q * 8];

    int sc = tid & 15;        // staging col 0..15
    int skg = tid >> 4;       // staging k-group 0..15

    for (int w = 0; w < 17; w++) {
        const float* W = (w < 16) ? (w2 + w * 1024) : self2;
        // stage W2 transposed: wsT[col(16)][k(64)]
        {
            int k0 = skg * 4;
            unsigned p0 = (unsigned)f2bf(W[k0 * 16 + sc]) | ((unsigned)f2bf(W[(k0 + 1) * 16 + sc]) << 16);
            unsigned p1 = (unsigned)f2bf(W[(k0 + 2) * 16 + sc]) | ((unsigned)f2bf(W[(k0 + 3) * 16 + sc]) << 16);
            *(unsigned*)&wsT[sc][k0] = p0;
            *(unsigned*)&wsT[sc][k0 + 2] = p1;
        }
        __syncthreads();

        f4v acc = (f4v){0.f, 0.f, 0.f, 0.f};
        s8v b0 = *(const s8v*)&wsT[m][q * 8];
        s8v b1 = *(const s8v*)&wsT[m][32 + q * 8];
        acc = __builtin_amdgcn_mfma_f32_16x16x32_bf16(a0, b0, acc, 0, 0, 0);
        acc = __builtin_amdgcn_mfma_f32_16x16x32_bf16(a1, b1, acc, 0, 0, 0);

        if (w < 16) {
            #pragma unroll
            for (int r = 0; r < 4; r++) outs[wv * 16 + q * 4 + r][m] = f2bf(acc[r]);
            __syncthreads();
            int row = tid >> 2, cq = tid & 3;
            int n = n0 + row;
            if (n < N_NODES) {
                int2 d = *(const int2*)&outs[row][cq * 4];
                *(int2*)(t2 + ((size_t)w * N_NODES + n) * 16 + cq * 4) = d;
            }
        } else {
            // self term: direct fp32 stores to out
            #pragma unroll
            for (int r = 0; r < 4; r++) {
                int n = n0 + wv * 16 + q * 4 + r;
                if (n < N_NODES) out[(size_t)n * 16 + m] = acc[r];
            }
            __syncthreads();
        }
    }
}

// ---------------- layer-2 aggregation: quarter-wave per dst node ----------------
__global__ __launch_bounds__(256) void k_agg2(const int* __restrict__ offsets,
                                              const int2* __restrict__ sedge,
                                              const unsigned short* __restrict__ t2,
                                              float* __restrict__ out) {
    int tid = threadIdx.x;
    int n = blockIdx.x * 16 + (tid >> 4);
    int l = tid & 15;
    int start = offsets[n];
    int end = offsets[n + 1];
    float acc = 0.f;
    for (int i = start; i < end; i++) {
        int2 e = sedge[i];
        float inv = __int_as_float(e.y);
        acc += inv * bf2f(t2[(size_t)e.x * 16 + l]);
    }
    out[(size_t)n * 16 + l] += acc;
}

extern "C" void kernel_launch(void* const* d_in, const int* in_sizes, int n_in,
                              void* d_out, int out_size, void* d_ws, size_t ws_size,
                              hipStream_t stream) {
    const float* x      = (const float*)d_in[0];
    const float* bases1 = (const float*)d_in[1];
    const float* coeffs1= (const float*)d_in[2];
    const float* self1  = (const float*)d_in[3];
    const float* bases2 = (const float*)d_in[4];
    const float* coeffs2= (const float*)d_in[5];
    const float* self2  = (const float*)d_in[6];
    const int*   ei     = (const int*)d_in[7];
    const int*   et     = (const int*)d_in[8];
    float* out = (float*)d_out;

    char* ws = (char*)d_ws;
    // workspace (~119.1 MB total)
    int*            counts  = (int*)(ws + 0);              //   3,200,000
    int*            offsets = (int*)(ws + 3200000);        //     200,064
    int*            cursor  = (int*)(ws + 3400064);        //     200,064
    float*          w1      = (float*)(ws + 3600128);      //     262,144
    float*          w2      = (float*)(ws + 3862272);      //      65,536
    int*            bsum    = (int*)(ws + 3927808);        //       1,024
    int2*           sedge   = (int2*)(ws + 3928832);       //   6,400,000
    unsigned short* h       = (unsigned short*)(ws + 10328832);  //   6,400,000
    unsigned short* t1      = (unsigned short*)(ws + 16728832);  // 102,400,000 -> end 119,128,832
    unsigned short* t2      = t1;                          // alias: t1 dead after k_agg1

    hipMemsetAsync(counts, 0, 3200000, stream);
    k_counts<<<(N_EDGES + 255) / 256, 256, 0, stream>>>(et, ei, counts);
    k_wrel<<<(N_REL * D_IN * D_HID + N_REL * D_HID * N_CLASS + 255) / 256, 256, 0, stream>>>(
        bases1, coeffs1, bases2, coeffs2, w1, w2);
    k_scan_local<<<N_SBLK, 256, 0, stream>>>(counts, offsets, bsum);
    k_scan_bsum<<<1, 256, 0, stream>>>(bsum);
    k_scan_final<<<N_SBLK, 256, 0, stream>>>(offsets, bsum, cursor);
    k_scatter<<<(N_EDGES + 255) / 256, 256, 0, stream>>>(ei, et, counts, cursor, sedge);
    k_gemm1<<<(N_NODES + 63) / 64, 256, 0, stream>>>(x, w1, self1, t1, h);
    k_agg1<<<12500, 256, 0, stream>>>(offsets, sedge, t1, h);
    k_gemm2<<<(N_NODES + 63) / 64, 256, 0, stream>>>(h, w2, self2, t2, out);
    k_agg2<<<3125, 256, 0, stream>>>(offsets, sedge, t2, out);
}

// Round 5
// 263.666 us; speedup vs baseline: 4.7463x; 1.2374x over previous
//
#include <hip/hip_runtime.h>

#define N_NODES 50000
#define N_REL 16
#define N_BASIS 8
#define D_IN 64
#define D_HID 64
#define N_CLASS 16
#define N_EDGES 800000
#define N_SBLK 196   // ceil(50000/256)

typedef short s8v __attribute__((ext_vector_type(8)));    // 8 bf16 (4 VGPRs) MFMA A/B frag
typedef float f4v __attribute__((ext_vector_type(4)));    // 4 fp32 MFMA C/D frag

__device__ inline unsigned short f2bf(float f) {
    union { float f; unsigned u; } v; v.f = f;
    unsigned r = (v.u + 0x7FFFu + ((v.u >> 16) & 1u)) >> 16;   // RNE
    return (unsigned short)r;
}
__device__ inline float bf2f(unsigned short b) {
    union { unsigned u; float f; } v; v.u = ((unsigned)b) << 16;
    return v.f;
}

// ---------------- histogram: counts[r,n] ----------------
__global__ __launch_bounds__(256) void k_counts(const int* __restrict__ et,
                                                const int* __restrict__ ei,
                                                int* __restrict__ counts) {
    int e = blockIdx.x * 256 + threadIdx.x;
    if (e < N_EDGES) {
        int dst = ei[N_EDGES + e];
        int t = et[e];
        atomicAdd(&counts[t * N_NODES + dst], 1);
    }
}

// ---------------- W_r = sum_b coeffs[r,b] * bases[b] ----------------
__global__ __launch_bounds__(256) void k_wrel(const float* __restrict__ b1, const float* __restrict__ c1,
                                              const float* __restrict__ b2, const float* __restrict__ c2,
                                              float* __restrict__ w1, float* __restrict__ w2) {
    int idx = blockIdx.x * 256 + threadIdx.x;
    if (idx < N_REL * D_IN * D_HID) {
        int r = idx >> 12;
        int io = idx & 4095;
        float acc = 0.f;
        #pragma unroll
        for (int b = 0; b < N_BASIS; b++) acc += c1[r * N_BASIS + b] * b1[b * 4096 + io];
        w1[idx] = acc;
    }
    int idx2 = idx - N_REL * D_IN * D_HID;
    if (idx2 >= 0 && idx2 < N_REL * D_HID * N_CLASS) {
        int r = idx2 >> 10;
        int io = idx2 & 1023;
        float acc = 0.f;
        #pragma unroll
        for (int b = 0; b < N_BASIS; b++) acc += c2[r * N_BASIS + b] * b2[b * 1024 + io];
        w2[idx2] = acc;
    }
}

// ---------------- scan stage 1 ----------------
__global__ __launch_bounds__(256) void k_scan_local(const int* __restrict__ counts,
                                                    int* __restrict__ offsets,
                                                    int* __restrict__ bsum) {
    __shared__ int s[256];
    int t = threadIdx.x;
    int i = blockIdx.x * 256 + t;
    int v = 0;
    if (i < N_NODES) {
        #pragma unroll
        for (int r = 0; r < N_REL; r++) v += counts[r * N_NODES + i];
    }
    s[t] = v;
    __syncthreads();
    #pragma unroll
    for (int off = 1; off < 256; off <<= 1) {
        int x = (t >= off) ? s[t - off] : 0;
        __syncthreads();
        s[t] += x;
        __syncthreads();
    }
    if (i < N_NODES) offsets[i] = s[t] - v;
    if (t == 255) bsum[blockIdx.x] = s[255];
}

// ---------------- scan stage 2 ----------------
__global__ __launch_bounds__(256) void k_scan_bsum(int* __restrict__ bsum) {
    __shared__ int s[256];
    int t = threadIdx.x;
    int v = (t < N_SBLK) ? bsum[t] : 0;
    s[t] = v;
    __syncthreads();
    #pragma unroll
    for (int off = 1; off < 256; off <<= 1) {
        int x = (t >= off) ? s[t - off] : 0;
        __syncthreads();
        s[t] += x;
        __syncthreads();
    }
    if (t < N_SBLK) bsum[t] = s[t] - v;
}

// ---------------- scan stage 3 ----------------
__global__ __launch_bounds__(256) void k_scan_final(int* __restrict__ offsets,
                                                    const int* __restrict__ bsum,
                                                    int* __restrict__ cursor) {
    int i = blockIdx.x * 256 + threadIdx.x;
    if (i < N_NODES) {
        int o = offsets[i] + bsum[blockIdx.x];
        offsets[i] = o;
        cursor[i] = o;
    }
    if (i == 0) offsets[N_NODES] = N_EDGES;
}

// ---------------- scatter edges into dst-sorted order (packed int2) ----------------
__global__ __launch_bounds__(256) void k_scatter(const int* __restrict__ ei, const int* __restrict__ et,
                                                 const int* __restrict__ counts,
                                                 int* __restrict__ cursor,
                                                 int2* __restrict__ sedge) {
    int e = blockIdx.x * 256 + threadIdx.x;
    if (e >= N_EDGES) return;
    int src = ei[e];
    int dst = ei[N_EDGES + e];
    int t = et[e];
    int pos = atomicAdd(&cursor[dst], 1);
    float inv = 1.0f / (float)counts[t * N_NODES + dst];
    sedge[pos] = make_int2(t * N_NODES + src, __float_as_int(inv));
}

// ---------------- layer-1 MFMA transform ----------------
__global__ __launch_bounds__(256) void k_gemm1(const float* __restrict__ x, const float* __restrict__ w1,
                                               const float* __restrict__ self1,
                                               unsigned short* __restrict__ t1, unsigned short* __restrict__ h) {
    __shared__ __align__(16) unsigned short xs[64][72];
    __shared__ __align__(16) unsigned short wsT[64][72];
    __shared__ __align__(16) unsigned short outs[64][72];
    int tid = threadIdx.x;
    int n0 = blockIdx.x * 64;
    int wv = tid >> 6, lane = tid & 63;
    int m = lane & 15, q = lane >> 4;

    #pragma unroll
    for (int i = 0; i < 16; i++) {
        int idx = tid + i * 256;
        int r = idx >> 6, c = idx & 63;
        int n = n0 + r;
        float v = (n < N_NODES) ? x[(size_t)n * 64 + c] : 0.f;
        xs[r][c] = f2bf(v);
    }
    __syncthreads();

    s8v a0 = *(const s8v*)&xs[wv * 16 + m][q * 8];
    s8v a1 = *(const s8v*)&xs[wv * 16 + m][32 + q * 8];

    int sc = tid & 63;
    int skg = tid >> 6;

    for (int w = 0; w < 17; w++) {
        const float* W = (w < 16) ? (w1 + w * 4096) : self1;
        #pragma unroll
        for (int jp = 0; jp < 8; jp++) {
            int k = skg * 16 + jp * 2;
            unsigned pk = (unsigned)f2bf(W[k * 64 + sc]) | ((unsigned)f2bf(W[(k + 1) * 64 + sc]) << 16);
            *(unsigned*)&wsT[sc][k] = pk;
        }
        __syncthreads();

        f4v acc[4];
        #pragma unroll
        for (int ct = 0; ct < 4; ct++) {
            acc[ct] = (f4v){0.f, 0.f, 0.f, 0.f};
            s8v b0 = *(const s8v*)&wsT[ct * 16 + m][q * 8];
            s8v b1 = *(const s8v*)&wsT[ct * 16 + m][32 + q * 8];
            acc[ct] = __builtin_amdgcn_mfma_f32_16x16x32_bf16(a0, b0, acc[ct], 0, 0, 0);
            acc[ct] = __builtin_amdgcn_mfma_f32_16x16x32_bf16(a1, b1, acc[ct], 0, 0, 0);
        }
        #pragma unroll
        for (int ct = 0; ct < 4; ct++) {
            #pragma unroll
            for (int r = 0; r < 4; r++) {
                outs[wv * 16 + q * 4 + r][ct * 16 + m] = f2bf(acc[ct][r]);
            }
        }
        __syncthreads();

        int row = tid >> 2, cq = tid & 3;
        int n = n0 + row;
        if (n < N_NODES) {
            int4 d0 = *(const int4*)&outs[row][cq * 16];
            int4 d1 = *(const int4*)&outs[row][cq * 16 + 8];
            unsigned short* dst = (w < 16) ? (t1 + ((size_t)w * N_NODES + n) * 64 + cq * 16)
                                           : (h + (size_t)n * 64 + cq * 16);
            *(int4*)dst = d0;
            *(int4*)(dst + 8) = d1;
        }
    }
}

// ---------------- layer-1 aggregation: 1 wave/node, 4 edges in flight ----------------
__global__ __launch_bounds__(256) void k_agg1(const int* __restrict__ offsets,
                                              const int2* __restrict__ sedge,
                                              const unsigned short* __restrict__ t1,
                                              unsigned short* __restrict__ h) {
    int tid = threadIdx.x;
    int n = blockIdx.x * 4 + (tid >> 6);
    int lane = tid & 63;
    int qe = lane >> 4;       // edge slot 0..3
    int d16 = lane & 15;      // dim group: 4 bf16 each
    int start = offsets[n];
    int end = offsets[n + 1];
    float a0 = 0.f, a1 = 0.f, a2 = 0.f, a3 = 0.f;
    for (int i = start + qe; i < end; i += 4) {
        int2 e = sedge[i];
        float inv = __int_as_float(e.y);
        ushort4 v = *(const ushort4*)(t1 + (size_t)e.x * 64 + d16 * 4);
        a0 += inv * bf2f(v.x);
        a1 += inv * bf2f(v.y);
        a2 += inv * bf2f(v.z);
        a3 += inv * bf2f(v.w);
    }
    // reduce across the 4 edge slots (lane bits 4,5)
    a0 += __shfl_xor(a0, 16, 64); a1 += __shfl_xor(a1, 16, 64);
    a2 += __shfl_xor(a2, 16, 64); a3 += __shfl_xor(a3, 16, 64);
    a0 += __shfl_xor(a0, 32, 64); a1 += __shfl_xor(a1, 32, 64);
    a2 += __shfl_xor(a2, 32, 64); a3 += __shfl_xor(a3, 32, 64);
    if (qe == 0) {
        size_t hi = (size_t)n * 64 + d16 * 4;
        ushort4 hv = *(const ushort4*)(h + hi);
        ushort4 o;
        o.x = f2bf(bf2f(hv.x) + a0);
        o.y = f2bf(bf2f(hv.y) + a1);
        o.z = f2bf(bf2f(hv.z) + a2);
        o.w = f2bf(bf2f(hv.w) + a3);
        *(ushort4*)(h + hi) = o;
    }
}

// ---------------- layer-2 MFMA transform ----------------
__global__ __launch_bounds__(256) void k_gemm2(const unsigned short* __restrict__ h, const float* __restrict__ w2,
                                               const float* __restrict__ self2,
                                               unsigned short* __restrict__ t2, float* __restrict__ out) {
    __shared__ __align__(16) unsigned short xs[64][72];
    __shared__ __align__(16) unsigned short wsT[16][72];
    __shared__ __align__(16) unsigned short outs[64][24];
    int tid = threadIdx.x;
    int n0 = blockIdx.x * 64;
    int wv = tid >> 6, lane = tid & 63;
    int m = lane & 15, q = lane >> 4;

    const unsigned* hb = (const unsigned*)h;
    #pragma unroll
    for (int i = 0; i < 8; i++) {
        int idx = tid + i * 256;
        int r = idx >> 5, c2 = idx & 31;
        int n = n0 + r;
        unsigned v = (n < N_NODES) ? hb[(size_t)n * 32 + c2] : 0u;
        unsigned lo = v & 0xFFFFu, hi = v >> 16;
        if (lo & 0x8000u) lo = 0u;
        if (hi & 0x8000u) hi = 0u;
        *(unsigned*)&xs[r][c2 * 2] = lo | (hi << 16);
    }
    __syncthreads();

    s8v a0 = *(const s8v*)&xs[wv * 16 + m][q * 8];
    s8v a1 = *(const s8v*)&xs[wv * 16 + m][32 + q * 8];

    int sc = tid & 15;
    int skg = tid >> 4;

    for (int w = 0; w < 17; w++) {
        const float* W = (w < 16) ? (w2 + w * 1024) : self2;
        {
            int k0 = skg * 4;
            unsigned p0 = (unsigned)f2bf(W[k0 * 16 + sc]) | ((unsigned)f2bf(W[(k0 + 1) * 16 + sc]) << 16);
            unsigned p1 = (unsigned)f2bf(W[(k0 + 2) * 16 + sc]) | ((unsigned)f2bf(W[(k0 + 3) * 16 + sc]) << 16);
            *(unsigned*)&wsT[sc][k0] = p0;
            *(unsigned*)&wsT[sc][k0 + 2] = p1;
        }
        __syncthreads();

        f4v acc = (f4v){0.f, 0.f, 0.f, 0.f};
        s8v b0 = *(const s8v*)&wsT[m][q * 8];
        s8v b1 = *(const s8v*)&wsT[m][32 + q * 8];
        acc = __builtin_amdgcn_mfma_f32_16x16x32_bf16(a0, b0, acc, 0, 0, 0);
        acc = __builtin_amdgcn_mfma_f32_16x16x32_bf16(a1, b1, acc, 0, 0, 0);

        if (w < 16) {
            #pragma unroll
            for (int r = 0; r < 4; r++) outs[wv * 16 + q * 4 + r][m] = f2bf(acc[r]);
            __syncthreads();
            int row = tid >> 2, cq = tid & 3;
            int n = n0 + row;
            if (n < N_NODES) {
                int2 d = *(const int2*)&outs[row][cq * 4];
                *(int2*)(t2 + ((size_t)w * N_NODES + n) * 16 + cq * 4) = d;
            }
        } else {
            #pragma unroll
            for (int r = 0; r < 4; r++) {
                int n = n0 + wv * 16 + q * 4 + r;
                if (n < N_NODES) out[(size_t)n * 16 + m] = acc[r];
            }
            __syncthreads();
        }
    }
}

// ---------------- layer-2 aggregation: 16 lanes/node, 4 edges in flight ----------------
__global__ __launch_bounds__(256) void k_agg2(const int* __restrict__ offsets,
                                              const int2* __restrict__ sedge,
                                              const unsigned short* __restrict__ t2,
                                              float* __restrict__ out) {
    int tid = threadIdx.x;
    int n = blockIdx.x * 16 + (tid >> 4);
    int sub = tid & 15;
    int qe = sub >> 2;        // edge slot 0..3 (lane bits 2,3)
    int d4 = sub & 3;         // dim group: 4 bf16 each
    int start = offsets[n];
    int end = offsets[n + 1];
    float a0 = 0.f, a1 = 0.f, a2 = 0.f, a3 = 0.f;
    for (int i = start + qe; i < end; i += 4) {
        int2 e = sedge[i];
        float inv = __int_as_float(e.y);
        ushort4 v = *(const ushort4*)(t2 + (size_t)e.x * 16 + d4 * 4);
        a0 += inv * bf2f(v.x);
        a1 += inv * bf2f(v.y);
        a2 += inv * bf2f(v.z);
        a3 += inv * bf2f(v.w);
    }
    a0 += __shfl_xor(a0, 4, 64); a1 += __shfl_xor(a1, 4, 64);
    a2 += __shfl_xor(a2, 4, 64); a3 += __shfl_xor(a3, 4, 64);
    a0 += __shfl_xor(a0, 8, 64); a1 += __shfl_xor(a1, 8, 64);
    a2 += __shfl_xor(a2, 8, 64); a3 += __shfl_xor(a3, 8, 64);
    if (qe == 0) {
        float* p = out + (size_t)n * 16 + d4 * 4;
        float4 cur = *(const float4*)p;
        cur.x += a0; cur.y += a1; cur.z += a2; cur.w += a3;
        *(float4*)p = cur;
    }
}

extern "C" void kernel_launch(void* const* d_in, const int* in_sizes, int n_in,
                              void* d_out, int out_size, void* d_ws, size_t ws_size,
                              hipStream_t stream) {
    const float* x      = (const float*)d_in[0];
    const float* bases1 = (const float*)d_in[1];
    const float* coeffs1= (const float*)d_in[2];
    const float* self1  = (const float*)d_in[3];
    const float* bases2 = (const float*)d_in[4];
    const float* coeffs2= (const float*)d_in[5];
    const float* self2  = (const float*)d_in[6];
    const int*   ei     = (const int*)d_in[7];
    const int*   et     = (const int*)d_in[8];
    float* out = (float*)d_out;

    char* ws = (char*)d_ws;
    int*            counts  = (int*)(ws + 0);              //   3,200,000
    int*            offsets = (int*)(ws + 3200000);        //     200,064
    int*            cursor  = (int*)(ws + 3400064);        //     200,064
    float*          w1      = (float*)(ws + 3600128);      //     262,144
    float*          w2      = (float*)(ws + 3862272);      //      65,536
    int*            bsum    = (int*)(ws + 3927808);        //       1,024
    int2*           sedge   = (int2*)(ws + 3928832);       //   6,400,000
    unsigned short* h       = (unsigned short*)(ws + 10328832);  //   6,400,000
    unsigned short* t1      = (unsigned short*)(ws + 16728832);  // 102,400,000 -> end 119,128,832
    unsigned short* t2      = t1;                          // alias: t1 dead after k_agg1

    hipMemsetAsync(counts, 0, 3200000, stream);
    k_counts<<<(N_EDGES + 255) / 256, 256, 0, stream>>>(et, ei, counts);
    k_wrel<<<(N_REL * D_IN * D_HID + N_REL * D_HID * N_CLASS + 255) / 256, 256, 0, stream>>>(
        bases1, coeffs1, bases2, coeffs2, w1, w2);
    k_scan_local<<<N_SBLK, 256, 0, stream>>>(counts, offsets, bsum);
    k_scan_bsum<<<1, 256, 0, stream>>>(bsum);
    k_scan_final<<<N_SBLK, 256, 0, stream>>>(offsets, bsum, cursor);
    k_scatter<<<(N_EDGES + 255) / 256, 256, 0, stream>>>(ei, et, counts, cursor, sedge);
    k_gemm1<<<(N_NODES + 63) / 64, 256, 0, stream>>>(x, w1, self1, t1, h);
    k_agg1<<<12500, 256, 0, stream>>>(offsets, sedge, t1, h);
    k_gemm2<<<(N_NODES + 63) / 64, 256, 0, stream>>>(h, w2, self2, t2, out);
    k_agg2<<<3125, 256, 0, stream>>>(offsets, sedge, t2, out);
}